// Round 2
// baseline (181.713 us; speedup 1.0000x reference)
//
#include <hip/hip_runtime.h>

#define HW 32
#define NPIX 1024      // 32*32
#define IMG 3072       // 3*32*32

// ---------------- threefry2x32 (exact JAX semantics) ----------------
__device__ __forceinline__ unsigned rotl32(unsigned x, int d) {
    return (x << d) | (x >> (32 - d));
}

struct UPair { unsigned a, b; };

__device__ __forceinline__ UPair threefry2x32(unsigned k0, unsigned k1,
                                              unsigned x0, unsigned x1) {
    unsigned k2 = k0 ^ k1 ^ 0x1BD11BDAu;
    x0 += k0; x1 += k1;
#define RND(r) { x0 += x1; x1 = rotl32(x1, (r)); x1 ^= x0; }
    RND(13) RND(15) RND(26) RND(6)
    x0 += k1; x1 += k2 + 1u;
    RND(17) RND(29) RND(16) RND(24)
    x0 += k2; x1 += k0 + 2u;
    RND(13) RND(15) RND(26) RND(6)
    x0 += k0; x1 += k1 + 3u;
    RND(17) RND(29) RND(16) RND(24)
    x0 += k1; x1 += k2 + 4u;
    RND(13) RND(15) RND(26) RND(6)
    x0 += k2; x1 += k0 + 5u;
#undef RND
    return {x0, x1};
}

__device__ __forceinline__ float bits_to_u01(unsigned bits) {
    return __uint_as_float((bits >> 9) | 0x3f800000u) - 1.0f;
}

// reference _reflect with lo=-0.5, span=32
__device__ __forceinline__ float reflect32(float c) {
    float t = fabsf(c + 0.5f);
    float extra = fmodf(t, 32.0f);
    float flips = floorf(t * 0.03125f);
    float par = fmodf(flips, 2.0f);
    float o = (par == 0.0f) ? (extra - 0.5f) : (31.5f - extra);
    return fminf(fmaxf(o, 0.0f), 31.0f);
}

__global__ __launch_bounds__(256) void aug_kernel(
    const float* __restrict__ xin, const float* __restrict__ aff,
    const int* __restrict__ apply_crop, float* __restrict__ out, int B) {
    __shared__ __align__(16) float bufA[IMG];
    __shared__ __align__(16) float bufB[IMG];
    __shared__ float s_theta[6];
    __shared__ int s_top, s_left, s_flip, s_hue, s_gray, s_blur, s_solar;
    __shared__ float s_bright, s_contr, s_sat;

    const int b = blockIdx.x;
    const int t = threadIdx.x;
    const bool do_crop = (apply_crop[0] != 0);

    const float MEANc[3] = {0.5071f, 0.4867f, 0.4408f};
    const float STDc[3]  = {0.2675f, 0.2565f, 0.2761f};
    const float INVSTD[3] = {1.0f / 0.2675f, 1.0f / 0.2565f, 1.0f / 0.2761f};

    // ---- issue global image loads early ----
    const float4* imgv = (const float4*)(xin + (size_t)b * IMG);
    float4 ld0 = imgv[t];
    float4 ld1 = imgv[t + 256];
    float4 ld2 = imgv[t + 512];

    const size_t OUT_IMG = (size_t)B * IMG;
    if (t < 6) {  // theta into LDS + affine passthrough output
        float v = aff[b * 6 + t];
        s_theta[t] = v;
        out[OUT_IMG + (size_t)B + (size_t)b * 6 + t] = v;
    }

    // ---- per-image RNG (jax_threefry_partitionable=True semantics) ----
    // ks = split(key(42), 10): ks[k] = threefry(0,42, 0,k) full pair.
    // random_bits(key,32,(B,)): bits[b] = r.a ^ r.b, r = threefry(key, 0, b).
    // randint: _split(key) -> k2 = threefry(key,0,1) pair; val = bits(k2,b) & 7.
    if (t < 10) {
        int k = t;
        UPair K = threefry2x32(0u, 42u, 0u, (unsigned)k);  // ks[k]
        if (k < 2) {
            UPair k2 = threefry2x32(K.a, K.b, 0u, 1u);     // lower-bits child key
            UPair r = threefry2x32(k2.a, k2.b, 0u, (unsigned)b);
            int val = (int)((r.a ^ r.b) & 7u);
            if (k == 0) s_top = val; else s_left = val;
        } else {
            UPair r = threefry2x32(K.a, K.b, 0u, (unsigned)b);
            float u = bits_to_u01(r.a ^ r.b);
            if      (k == 2) s_flip  = (u < 0.5f);
            else if (k == 3) s_bright = 1.0f + (u - 0.5f) * 0.8f;
            else if (k == 4) s_contr  = 1.0f + (u - 0.5f) * 0.8f;
            else if (k == 5) s_sat    = 1.0f + (u - 0.5f) * 0.8f;
            else if (k == 6) s_hue   = (u < 0.5f);
            else if (k == 7) s_gray  = (u < 0.2f);
            else if (k == 8) s_blur  = (u < 0.5f);
            else             s_solar = (u < 0.1f);
        }
    }

    // ---- denormalize + stage into LDS ----
    {
        float4 v = ld0;
        v.x = v.x * STDc[0] + MEANc[0]; v.y = v.y * STDc[0] + MEANc[0];
        v.z = v.z * STDc[0] + MEANc[0]; v.w = v.w * STDc[0] + MEANc[0];
        ((float4*)bufA)[t] = v;
        v = ld1;
        v.x = v.x * STDc[1] + MEANc[1]; v.y = v.y * STDc[1] + MEANc[1];
        v.z = v.z * STDc[1] + MEANc[1]; v.w = v.w * STDc[1] + MEANc[1];
        ((float4*)bufA)[t + 256] = v;
        v = ld2;
        v.x = v.x * STDc[2] + MEANc[2]; v.y = v.y * STDc[2] + MEANc[2];
        v.z = v.z * STDc[2] + MEANc[2]; v.w = v.w * STDc[2] + MEANc[2];
        ((float4*)bufA)[t + 512] = v;
    }
    __syncthreads();

    if (t == 0) out[OUT_IMG + b] = s_flip ? 1.0f : 0.0f;

    float* cur = bufA;
    float* nxt = bufB;

    // ---- crop-resize (block-uniform branch) ----
    if (do_crop) {
        const int top = s_top, left = s_left;
#pragma unroll
        for (int m = 0; m < 4; ++m) {
            int s = t + 256 * m;
            int yi = s >> 5, xj = s & 31;
            float di = fmaxf(((float)yi + 0.5f) * 0.78125f - 0.5f, 0.0f);
            float dj = fmaxf(((float)xj + 0.5f) * 0.78125f - 0.5f, 0.0f);
            int i0 = (int)di; float ly = di - (float)i0; int i1 = min(i0 + 1, 24);
            int q0 = (int)dj; float lx = dj - (float)q0; int q1 = min(q0 + 1, 24);
            int r0 = (top + i0) * HW, r1 = (top + i1) * HW;
            int c0 = left + q0, c1 = left + q1;
            float w00 = (1.0f - ly) * (1.0f - lx), w01 = (1.0f - ly) * lx;
            float w10 = ly * (1.0f - lx), w11 = ly * lx;
#pragma unroll
            for (int c = 0; c < 3; ++c) {
                const float* p = cur + c * NPIX;
                nxt[c * NPIX + s] = p[r0 + c0] * w00 + p[r0 + c1] * w01 +
                                    p[r1 + c0] * w10 + p[r1 + c1] * w11;
            }
        }
        float* tp = cur; cur = nxt; nxt = tp;
        __syncthreads();
    }

    // ---- grid sample (flip folded into column index) + color chain ----
    {
        const int flip = s_flip, hue = s_hue, grayf = s_gray;
        const float br = s_bright, ct = s_contr, sa = s_sat;
        const float th0 = s_theta[0], th1 = s_theta[1], th2 = s_theta[2];
        const float th3 = s_theta[3], th4 = s_theta[4], th5 = s_theta[5];
#pragma unroll
        for (int m = 0; m < 4; ++m) {
            int s = t + 256 * m;
            int yi = s >> 5, xj = s & 31;
            float xn = ((float)xj + 0.5f) * 0.0625f - 1.0f;
            float yn = ((float)yi + 0.5f) * 0.0625f - 1.0f;
            float gx = th0 * xn + th1 * yn + th2;
            float gy = th3 * xn + th4 * yn + th5;
            float ix = reflect32(((gx + 1.0f) * 32.0f - 1.0f) * 0.5f);
            float iy = reflect32(((gy + 1.0f) * 32.0f - 1.0f) * 0.5f);
            float fy = floorf(iy), fx = floorf(ix);
            float wy = iy - fy, wx = ix - fx;
            int y0 = min(max((int)fy, 0), 31); int y1 = min(y0 + 1, 31);
            int x0 = min(max((int)fx, 0), 31); int x1 = min(x0 + 1, 31);
            if (flip) { x0 = 31 - x0; x1 = 31 - x1; }
            int r0 = y0 * HW, r1 = y1 * HW;
            float w00 = (1.0f - wy) * (1.0f - wx), w01 = (1.0f - wy) * wx;
            float w10 = wy * (1.0f - wx), w11 = wy * wx;
            float ch0, ch1, ch2;
            {
                const float* p = cur;
                ch0 = p[r0 + x0] * w00 + p[r0 + x1] * w01 +
                      p[r1 + x0] * w10 + p[r1 + x1] * w11;
            }
            {
                const float* p = cur + NPIX;
                ch1 = p[r0 + x0] * w00 + p[r0 + x1] * w01 +
                      p[r1 + x0] * w10 + p[r1 + x1] * w11;
            }
            {
                const float* p = cur + 2 * NPIX;
                ch2 = p[r0 + x0] * w00 + p[r0 + x1] * w01 +
                      p[r1 + x0] * w10 + p[r1 + x1] * w11;
            }
            // brightness
            ch0 *= br; ch1 *= br; ch2 *= br;
            // contrast
            float g = (ch0 + ch1 + ch2) * (1.0f / 3.0f);
            ch0 = g + (ch0 - g) * ct; ch1 = g + (ch1 - g) * ct; ch2 = g + (ch2 - g) * ct;
            // saturation
            g = (ch0 + ch1 + ch2) * (1.0f / 3.0f);
            ch0 = g + (ch0 - g) * sa; ch1 = g + (ch1 - g) * sa; ch2 = g + (ch2 - g) * sa;
            // hue: channel reverse
            if (hue) { float tmp = ch0; ch0 = ch2; ch2 = tmp; }
            // grayscale
            if (grayf) { g = (ch0 + ch1 + ch2) * (1.0f / 3.0f); ch0 = ch1 = ch2 = g; }
            nxt[s] = ch0; nxt[NPIX + s] = ch1; nxt[2 * NPIX + s] = ch2;
        }
        float* tp = cur; cur = nxt; nxt = tp;
        __syncthreads();
    }

    // ---- blur (edge-clamped 3x3) + solarize + clip + renorm + store ----
    {
        const int blur = s_blur, solar = s_solar;
        float* o = out + (size_t)b * IMG;
#pragma unroll
        for (int m = 0; m < 4; ++m) {
            int s = t + 256 * m;
            int yi = s >> 5, xj = s & 31;
            int ym = max(yi - 1, 0) * HW, yc = yi * HW, yp = min(yi + 1, 31) * HW;
            int xm = max(xj - 1, 0), xp = min(xj + 1, 31);
#pragma unroll
            for (int c = 0; c < 3; ++c) {
                const float* p = cur + c * NPIX;
                float v = p[yc + xj];
                float r = v;
                if (blur) {
                    float sum = p[ym + xm] + p[ym + xj] + p[ym + xp] +
                                p[yc + xm] + v          + p[yc + xp] +
                                p[yp + xm] + p[yp + xj] + p[yp + xp];
                    r = sum * (1.0f / 9.0f);
                }
                if (solar && r > 0.5f) r = 1.0f - r;
                r = fminf(fmaxf(r, 0.0f), 1.0f);
                r = (r - MEANc[c]) * INVSTD[c];
                o[c * NPIX + s] = r;
            }
        }
    }
}

extern "C" void kernel_launch(void* const* d_in, const int* in_sizes, int n_in,
                              void* d_out, int out_size, void* d_ws, size_t ws_size,
                              hipStream_t stream) {
    const float* x = (const float*)d_in[0];
    const float* aff = (const float*)d_in[1];
    const int* ac = (const int*)d_in[2];
    float* out = (float*)d_out;
    int B = in_sizes[0] / IMG;
    aug_kernel<<<dim3(B), dim3(256), 0, stream>>>(x, aff, ac, out, B);
}